// Round 3
// baseline (245.906 us; speedup 1.0000x reference)
//
#include <hip/hip_runtime.h>
#include <hip/hip_bf16.h>

// B=2, IMG_DIM=VOXEL_DIM=QK_DIM=256, H=W=64, N=4096.
// Inputs/outputs FP32; internal GEMMs bf16 MFMA (16x16x32).

typedef __hip_bfloat16 bf16;
typedef __attribute__((ext_vector_type(8))) short bf16x8;   // 8 bf16 = 4 VGPRs
typedef __attribute__((ext_vector_type(4))) float f32x4;

#define AS1 __attribute__((address_space(1)))
#define AS3 __attribute__((address_space(3)))

__device__ __forceinline__ void gld_lds16(const bf16* g, bf16* s) {
    // async global->LDS, 16B/lane; LDS dst = wave-uniform base + lane*16
    __builtin_amdgcn_global_load_lds((const AS1 void*)g, (AS3 void*)s, 16, 0, 0);
}

__device__ __forceinline__ bf16x8 cvt8(const float* __restrict__ p) {
    const float4 a = *(const float4*)p;
    const float4 b = *(const float4*)(p + 4);
    bf16 t[8];
    t[0] = __float2bfloat16(a.x); t[1] = __float2bfloat16(a.y);
    t[2] = __float2bfloat16(a.z); t[3] = __float2bfloat16(a.w);
    t[4] = __float2bfloat16(b.x); t[5] = __float2bfloat16(b.y);
    t[6] = __float2bfloat16(b.z); t[7] = __float2bfloat16(b.w);
    return *(const bf16x8*)t;
}

// ---------------------------------------------------------------------------
// Kernel 1: projections. 512 blocks: blk = s*256 + b*128 + g*64 + ntile.
// Each block: one 64-position x 256-outch GEMM (g=0: Q/Kt; g=1: V).
// XT staged with coalesced float4 gathers (both layouts).
// ---------------------------------------------------------------------------
__global__ __launch_bounds__(256) void proj_kernel(
    const float* __restrict__ img, const float* __restrict__ pc,
    const float* __restrict__ Wq,  const float* __restrict__ bq,
    const float* __restrict__ Wk,  const float* __restrict__ bk,
    const float* __restrict__ Wvi, const float* __restrict__ bvi,
    const float* __restrict__ Wvp, const float* __restrict__ bvp,
    bf16* __restrict__ Qw, bf16* __restrict__ Ktw, bf16* __restrict__ Vall)
{
    __shared__ __align__(16) bf16 XT[64][264];   // [pos][cin], +8 pad

    const int blk = blockIdx.x;
    const int s   = blk >> 8;
    const int b   = (blk >> 7) & 1;
    const int g   = (blk >> 6) & 1;
    const int n0  = (blk & 63) * 64;
    const int tid = threadIdx.x;

    if (s == 0) {
        const float* src = img + b * 1048576;                 // [256][4096]
        for (int k = 0; k < 16; k++) {
            const int i = tid + k * 256;
            const int cin = i >> 4, nl4 = (i & 15) * 4;
            const float4 v = *(const float4*)&src[cin * 4096 + n0 + nl4];
            XT[nl4 + 0][cin] = __float2bfloat16(v.x);
            XT[nl4 + 1][cin] = __float2bfloat16(v.y);
            XT[nl4 + 2][cin] = __float2bfloat16(v.z);
            XT[nl4 + 3][cin] = __float2bfloat16(v.w);
        }
    } else {
        // pc[b][d][h][w][c]: ch = c*16+d, flat = d*65536 + n*16 + c
        const float* src = pc + b * 1048576;
        for (int k = 0; k < 16; k++) {
            const int d = k, u = tid;
            const int nl = u >> 2, c4 = (u & 3) * 4;
            const float4 v = *(const float4*)&src[d * 65536 + (n0 + nl) * 16 + c4];
            XT[nl][(c4 + 0) * 16 + d] = __float2bfloat16(v.x);
            XT[nl][(c4 + 1) * 16 + d] = __float2bfloat16(v.y);
            XT[nl][(c4 + 2) * 16 + d] = __float2bfloat16(v.z);
            XT[nl][(c4 + 3) * 16 + d] = __float2bfloat16(v.w);
        }
    }
    __syncthreads();

    const float* W = s ? (g ? Wvp : Wk) : (g ? Wvi : Wq);
    const float* Bv = s ? (g ? bvp : bk) : (g ? bvi : bq);

    const int wv = tid >> 6, lane = tid & 63, l16 = lane & 15, quad = lane >> 4;
    const int ob = wv * 64;

    f32x4 acc[4][4] = {};

    for (int ks = 0; ks < 8; ks++) {
        const int k0 = ks * 32;
        bf16x8 af[4], wf[4];
        for (int ti = 0; ti < 4; ti++)
            af[ti] = *(const bf16x8*)&XT[ti * 16 + l16][k0 + quad * 8];
        for (int tj = 0; tj < 4; tj++)
            wf[tj] = cvt8(&W[(ob + tj * 16 + l16) * 256 + k0 + quad * 8]);
        for (int ti = 0; ti < 4; ti++)
            for (int tj = 0; tj < 4; tj++)
                acc[ti][tj] = __builtin_amdgcn_mfma_f32_16x16x32_bf16(af[ti], wf[tj], acc[ti][tj], 0, 0, 0);
    }

    if (g == 0) {
        bf16* D1 = (s ? Ktw : Qw) + b * (4096 * 256);          // [n][o]
        for (int tj = 0; tj < 4; tj++) {
            const int o = ob + tj * 16 + l16;
            const float bias = Bv[o];
            for (int ti = 0; ti < 4; ti++) {
                const int nl = ti * 16 + quad * 4;             // D row = quad*4+r
                for (int r = 0; r < 4; r++)
                    D1[(n0 + nl + r) * 256 + o] = __float2bfloat16(acc[ti][tj][r] + bias);
            }
        }
    } else {
        bf16* D2 = Vall + b * (512 * 4096) + (s ? 256 * 4096 : 0);  // [c'][p]
        for (int tj = 0; tj < 4; tj++) {
            const int o = ob + tj * 16 + l16;
            const float bias = Bv[o];
            for (int ti = 0; ti < 4; ti++) {
                const int nl = ti * 16 + quad * 4;
                bf16 pv[4];
                for (int r = 0; r < 4; r++)
                    pv[r] = __float2bfloat16(acc[ti][tj][r] + bias);
                *(uint2*)&D2[o * 4096 + n0 + nl] = *(const uint2*)pv;
            }
        }
    }
}

// ---------------------------------------------------------------------------
// Kernel 2: S = Q.Kt^T (NT, K=256) -> Pt = exp(S) (bf16) + non-atomic
// Lpart[b][q][strip] (strip = 64-wide p range). No max-subtraction (|S|<=~10;
// clamp 80 inert). Shuffle-reduce replaces all atomics.
// ---------------------------------------------------------------------------
__global__ __launch_bounds__(256) void attn_s_kernel(
    const bf16* __restrict__ Qw, const bf16* __restrict__ Ktw,
    bf16* __restrict__ Pt, float* __restrict__ Lpart)
{
    __shared__ __align__(16) bf16 As[128 * 32];
    __shared__ __align__(16) bf16 Bs[128 * 32];

    const int b  = blockIdx.z;
    const int q0 = blockIdx.y * 128;
    const int p0 = blockIdx.x * 128;
    const bf16* A = Qw  + b * (4096 * 256);
    const bf16* B = Ktw + b * (4096 * 256);

    const int tid = threadIdx.x;
    const int wv = tid >> 6, lane = tid & 63, l16 = lane & 15, quad = lane >> 4;
    const int wr = wv >> 1, wc = wv & 1;

    f32x4 acc[4][4] = {};

    for (int ks = 0; ks < 8; ks++) {
        const int k0 = ks * 32;
        bf16x8 av[2], bv[2];
        for (int c = 0; c < 2; c++) {
            const int ci = c * 256 + tid;
            const int row = ci >> 2, kc = ci & 3;
            av[c] = *(const bf16x8*)&A[(q0 + row) * 256 + k0 + kc * 8];
            bv[c] = *(const bf16x8*)&B[(p0 + row) * 256 + k0 + kc * 8];
        }
        __syncthreads();
        for (int c = 0; c < 2; c++) {
            const int ci = c * 256 + tid;
            *(bf16x8*)&As[ci * 8] = av[c];
            *(bf16x8*)&Bs[ci * 8] = bv[c];
        }
        __syncthreads();
        bf16x8 af[4], bfr[4];
        for (int t = 0; t < 4; t++) {
            af[t]  = *(const bf16x8*)&As[(wr * 64 + t * 16 + l16) * 32 + quad * 8];
            bfr[t] = *(const bf16x8*)&Bs[(wc * 64 + t * 16 + l16) * 32 + quad * 8];
        }
        for (int ti = 0; ti < 4; ti++)
            for (int tj = 0; tj < 4; tj++)
                acc[ti][tj] = __builtin_amdgcn_mfma_f32_16x16x32_bf16(af[ti], bfr[tj], acc[ti][tj], 0, 0, 0);
    }

    bf16* Pdst = Pt + (size_t)b * 4096 * 4096;
    const int strip = blockIdx.x * 2 + wc;                    // p strip of 64
    for (int ti = 0; ti < 4; ti++) {
        for (int r = 0; r < 4; r++) {
            const int qrow = wr * 64 + ti * 16 + quad * 4 + r;
            const int q = q0 + qrow;
            float partial = 0.0f;
            for (int tj = 0; tj < 4; tj++) {
                const float e = __expf(fminf(acc[ti][tj][r], 80.0f));
                partial += e;
                Pdst[(size_t)q * 4096 + p0 + wc * 64 + tj * 16 + l16] = __float2bfloat16(e);
            }
            // reduce over the 16 lanes of this quad (same qrow)
            partial += __shfl_xor(partial, 1);
            partial += __shfl_xor(partial, 2);
            partial += __shfl_xor(partial, 4);
            partial += __shfl_xor(partial, 8);
            if (l16 == 0)
                Lpart[(size_t)(b * 4096 + q) * 64 + strip] = partial;
        }
    }
}

// ---------------------------------------------------------------------------
// Kernel 2b: Linv[b][q] = 1 / sum_strip Lpart  (8192 rows)
// ---------------------------------------------------------------------------
__global__ __launch_bounds__(256) void lred_kernel(
    const float* __restrict__ Lpart, float* __restrict__ Linv)
{
    const int row = blockIdx.x * 256 + threadIdx.x;           // [0, 8192)
    const float4* lp = (const float4*)&Lpart[(size_t)row * 64];
    float s = 0.0f;
    for (int i = 0; i < 16; i++) {
        const float4 v = lp[i];
        s += v.x + v.y + v.z + v.w;
    }
    Linv[row] = 1.0f / fmaxf(s, 1e-30f);
}

// ---------------------------------------------------------------------------
// Kernel 3: O = Vall.Pt^T (NT) * Linv[q].
// v4: tile 256c x 128q, 4-way K-split (K=1024/block), 512 blocks x 512 thr
// (2 blocks/CU, 16 waves/CU). Staged traffic: 768 MB (v3) -> 403 MB; XCD
// chunk swizzle orders blocks so each XCD's 64-block chunk shares the Vall
// slab (16x L2 reuse) and the c-pair reads each Pt slab 2x via same L2.
// K-partials combined with fp32 atomic-fadd into zeroed output (<=4
// contributors/element). 2-phase counted-vmcnt pipeline + XOR swizzle as v3.
// ---------------------------------------------------------------------------
__global__ __launch_bounds__(512, 4) void attn_o_kernel(
    const bf16* __restrict__ Vall, const bf16* __restrict__ Pt,
    const float* __restrict__ Linv, float* __restrict__ out)
{
    // per buffer: As[256][32] @ 0 (16KB), Bs[128][32] @ 8192 (8KB) bf16 units
    __shared__ __align__(16) bf16 smem[2][12288];             // 48 KB

    // XCD chunk swizzle: 512 blocks, 8 XCDs, 64/chunk (512%8==0 -> bijective)
    const int orig = blockIdx.x;
    const int L = (orig & 7) * 64 + (orig >> 3);
    const int c  = L & 1;                                     // c-tile (2)
    const int q  = (L >> 1) & 31;                             // q-tile (32)
    const int kspl = (L >> 6) & 3;                            // K-split (4)
    const int b  = L >> 8;                                    // batch (2)

    const int c0 = c * 256;
    const int q0 = q * 128;
    const int kbase = kspl * 1024;

    const bf16* A = Vall + (size_t)b * 512 * 4096;
    const bf16* B = Pt   + (size_t)b * 4096 * 4096;

    const int tid = threadIdx.x;
    const int wv = tid >> 6, lane = tid & 63, l16 = lane & 15, quad = lane >> 4;
    const int wr = wv >> 1, wc = wv & 1;                      // wave: 64c x 64q

    // swizzled fragment-read offsets (bf16 units), constant over ks
    int aoff[4], boff[4];
    for (int t = 0; t < 4; t++) {
        const int rowa = wr * 64 + t * 16 + l16;
        aoff[t] = rowa * 32 + (quad ^ ((rowa >> 1) & 3)) * 8;
        const int rowb = wc * 64 + t * 16 + l16;
        boff[t] = rowb * 32 + (quad ^ ((rowb >> 1) & 3)) * 8;
    }

    const int arow = tid >> 2;                                // staged row [0,128)
    const int kswz = ((tid & 3) ^ ((arow >> 1) & 3)) * 8;     // pre-swizzled k chunk
    const bf16* Ag0 = A + (c0 + arow) * 4096 + kbase + kswz;
    const bf16* Ag1 = A + (c0 + 128 + arow) * 4096 + kbase + kswz;
    const bf16* Bg  = B + (size_t)(q0 + arow) * 4096 + kbase + kswz;

    f32x4 acc[4][4] = {};

#define STAGE(buf, ks)                                                  \
    do {                                                                \
        const int _k = (ks) * 32;                                       \
        bf16* _s = &smem[(buf)][0];                                     \
        gld_lds16(Ag0 + _k, _s + tid * 8);                              \
        gld_lds16(Ag1 + _k, _s + 4096 + tid * 8);                       \
        gld_lds16(Bg  + _k, _s + 8192 + tid * 8);                       \
    } while (0)

    STAGE(0, 0);
    int cur = 0;
    for (int ks = 0; ks < 32; ks++) {
        if (ks + 1 < 32) {
            STAGE(cur ^ 1, ks + 1);
            asm volatile("s_waitcnt vmcnt(3)" ::: "memory");  // cur's 3 landed
        } else {
            asm volatile("s_waitcnt vmcnt(0)" ::: "memory");
        }
        __builtin_amdgcn_s_barrier();                         // all waves' cur landed
        __builtin_amdgcn_sched_barrier(0);

        const bf16* As_ = &smem[cur][0];
        const bf16* Bs_ = &smem[cur][8192];
        bf16x8 af[4], bfr[4];
        for (int t = 0; t < 4; t++) af[t]  = *(const bf16x8*)&As_[aoff[t]];
        for (int t = 0; t < 4; t++) bfr[t] = *(const bf16x8*)&Bs_[boff[t]];
        __builtin_amdgcn_s_setprio(1);
        for (int ti = 0; ti < 4; ti++)
            for (int tj = 0; tj < 4; tj++)
                acc[ti][tj] = __builtin_amdgcn_mfma_f32_16x16x32_bf16(af[ti], bfr[tj], acc[ti][tj], 0, 0, 0);
        __builtin_amdgcn_s_setprio(0);

        asm volatile("s_waitcnt lgkmcnt(0)" ::: "memory");    // LDS reads retired
        __builtin_amdgcn_s_barrier();                         // safe to overwrite cur
        cur ^= 1;
    }
#undef STAGE

    // Epilogue: scale by Linv[q], atomic-fadd into zeroed out (4 K-partials).
    float linv[4];
    for (int tj = 0; tj < 4; tj++)
        linv[tj] = Linv[b * 4096 + q0 + wc * 64 + tj * 16 + l16];

    float* outp = out + (c0 ? 2097152u : 0u) + (size_t)b * 1048576;
    for (int ti = 0; ti < 4; ti++) {
        for (int r = 0; r < 4; r++) {
            const int crow = wr * 64 + ti * 16 + quad * 4 + r;
            float* rowp = outp + (size_t)crow * 4096 + q0 + wc * 64;
            for (int tj = 0; tj < 4; tj++)
                __hip_atomic_fetch_add(&rowp[tj * 16 + l16],
                                       acc[ti][tj][r] * linv[tj],
                                       __ATOMIC_RELAXED, __HIP_MEMORY_SCOPE_AGENT);
        }
    }
}

// ---------------------------------------------------------------------------
// ws: [0,4)MB Q | [4,8)MB Kt | [8,16)MB Vall | [16,80)MB Pt |
//     [80,82)MB Lpart fp32 [2][4096][64] | [82MB,+32KB) Linv fp32 [2][4096]
// ---------------------------------------------------------------------------
extern "C" void kernel_launch(void* const* d_in, const int* in_sizes, int n_in,
                              void* d_out, int out_size, void* d_ws, size_t ws_size,
                              hipStream_t stream)
{
    const float* img = (const float*)d_in[0];
    const float* pc  = (const float*)d_in[1];
    const float* Wq  = (const float*)d_in[2];
    const float* bq  = (const float*)d_in[3];
    const float* Wk  = (const float*)d_in[4];
    const float* bk  = (const float*)d_in[5];
    const float* Wvi = (const float*)d_in[6];
    const float* bvi = (const float*)d_in[7];
    const float* Wvp = (const float*)d_in[8];
    const float* bvp = (const float*)d_in[9];

    char* ws = (char*)d_ws;
    bf16*  Qw    = (bf16*)(ws);
    bf16*  Ktw   = (bf16*)(ws + (4ull  << 20));
    bf16*  Vall  = (bf16*)(ws + (8ull  << 20));
    bf16*  Pt    = (bf16*)(ws + (16ull << 20));
    float* Lpart = (float*)(ws + (80ull << 20));
    float* Linv  = (float*)(ws + (82ull << 20));

    hipMemsetAsync(d_out, 0, (size_t)out_size, stream);       // atomic targets
    proj_kernel<<<512, 256, 0, stream>>>(img, pc, Wq, bq, Wk, bk,
                                         Wvi, bvi, Wvp, bvp, Qw, Ktw, Vall);
    attn_s_kernel<<<dim3(32, 32, 2), 256, 0, stream>>>(Qw, Ktw, Pt, Lpart);
    lred_kernel<<<32, 256, 0, stream>>>(Lpart, Linv);
    attn_o_kernel<<<512, 512, 0, stream>>>(Vall, Pt, Linv, (float*)d_out);
}

// Round 4
// 199.418 us; speedup vs baseline: 1.2331x; 1.2331x over previous
//
#include <hip/hip_runtime.h>
#include <hip/hip_bf16.h>

// B=2, IMG_DIM=VOXEL_DIM=QK_DIM=256, H=W=64, N=4096.
// Inputs/outputs FP32; internal GEMMs bf16 MFMA (16x16x32).

typedef __hip_bfloat16 bf16;
typedef __attribute__((ext_vector_type(8))) short bf16x8;   // 8 bf16 = 4 VGPRs
typedef __attribute__((ext_vector_type(4))) float f32x4;

#define AS1 __attribute__((address_space(1)))
#define AS3 __attribute__((address_space(3)))

__device__ __forceinline__ void gld_lds16(const bf16* g, bf16* s) {
    // async global->LDS, 16B/lane; LDS dst = wave-uniform base + lane*16
    __builtin_amdgcn_global_load_lds((const AS1 void*)g, (AS3 void*)s, 16, 0, 0);
}

__device__ __forceinline__ bf16x8 cvt8(const float* __restrict__ p) {
    const float4 a = *(const float4*)p;
    const float4 b = *(const float4*)(p + 4);
    bf16 t[8];
    t[0] = __float2bfloat16(a.x); t[1] = __float2bfloat16(a.y);
    t[2] = __float2bfloat16(a.z); t[3] = __float2bfloat16(a.w);
    t[4] = __float2bfloat16(b.x); t[5] = __float2bfloat16(b.y);
    t[6] = __float2bfloat16(b.z); t[7] = __float2bfloat16(b.w);
    return *(const bf16x8*)t;
}

// ---------------------------------------------------------------------------
// Kernel 1: projections. 512 blocks: blk = s*256 + b*128 + g*64 + ntile.
// Each block: one 64-position x 256-outch GEMM (g=0: Q/Kt; g=1: V).
// XT staged with coalesced float4 gathers (both layouts).
// ---------------------------------------------------------------------------
__global__ __launch_bounds__(256) void proj_kernel(
    const float* __restrict__ img, const float* __restrict__ pc,
    const float* __restrict__ Wq,  const float* __restrict__ bq,
    const float* __restrict__ Wk,  const float* __restrict__ bk,
    const float* __restrict__ Wvi, const float* __restrict__ bvi,
    const float* __restrict__ Wvp, const float* __restrict__ bvp,
    bf16* __restrict__ Qw, bf16* __restrict__ Ktw, bf16* __restrict__ Vall)
{
    __shared__ __align__(16) bf16 XT[64][264];   // [pos][cin], +8 pad

    const int blk = blockIdx.x;
    const int s   = blk >> 8;
    const int b   = (blk >> 7) & 1;
    const int g   = (blk >> 6) & 1;
    const int n0  = (blk & 63) * 64;
    const int tid = threadIdx.x;

    if (s == 0) {
        const float* src = img + b * 1048576;                 // [256][4096]
        for (int k = 0; k < 16; k++) {
            const int i = tid + k * 256;
            const int cin = i >> 4, nl4 = (i & 15) * 4;
            const float4 v = *(const float4*)&src[cin * 4096 + n0 + nl4];
            XT[nl4 + 0][cin] = __float2bfloat16(v.x);
            XT[nl4 + 1][cin] = __float2bfloat16(v.y);
            XT[nl4 + 2][cin] = __float2bfloat16(v.z);
            XT[nl4 + 3][cin] = __float2bfloat16(v.w);
        }
    } else {
        // pc[b][d][h][w][c]: ch = c*16+d, flat = d*65536 + n*16 + c
        const float* src = pc + b * 1048576;
        for (int k = 0; k < 16; k++) {
            const int d = k, u = tid;
            const int nl = u >> 2, c4 = (u & 3) * 4;
            const float4 v = *(const float4*)&src[d * 65536 + (n0 + nl) * 16 + c4];
            XT[nl][(c4 + 0) * 16 + d] = __float2bfloat16(v.x);
            XT[nl][(c4 + 1) * 16 + d] = __float2bfloat16(v.y);
            XT[nl][(c4 + 2) * 16 + d] = __float2bfloat16(v.z);
            XT[nl][(c4 + 3) * 16 + d] = __float2bfloat16(v.w);
        }
    }
    __syncthreads();

    const float* W = s ? (g ? Wvp : Wk) : (g ? Wvi : Wq);
    const float* Bv = s ? (g ? bvp : bk) : (g ? bvi : bq);

    const int wv = tid >> 6, lane = tid & 63, l16 = lane & 15, quad = lane >> 4;
    const int ob = wv * 64;

    f32x4 acc[4][4] = {};

    for (int ks = 0; ks < 8; ks++) {
        const int k0 = ks * 32;
        bf16x8 af[4], wf[4];
        for (int ti = 0; ti < 4; ti++)
            af[ti] = *(const bf16x8*)&XT[ti * 16 + l16][k0 + quad * 8];
        for (int tj = 0; tj < 4; tj++)
            wf[tj] = cvt8(&W[(ob + tj * 16 + l16) * 256 + k0 + quad * 8]);
        for (int ti = 0; ti < 4; ti++)
            for (int tj = 0; tj < 4; tj++)
                acc[ti][tj] = __builtin_amdgcn_mfma_f32_16x16x32_bf16(af[ti], wf[tj], acc[ti][tj], 0, 0, 0);
    }

    if (g == 0) {
        bf16* D1 = (s ? Ktw : Qw) + b * (4096 * 256);          // [n][o]
        for (int tj = 0; tj < 4; tj++) {
            const int o = ob + tj * 16 + l16;
            const float bias = Bv[o];
            for (int ti = 0; ti < 4; ti++) {
                const int nl = ti * 16 + quad * 4;             // D row = quad*4+r
                for (int r = 0; r < 4; r++)
                    D1[(n0 + nl + r) * 256 + o] = __float2bfloat16(acc[ti][tj][r] + bias);
            }
        }
    } else {
        bf16* D2 = Vall + b * (512 * 4096) + (s ? 256 * 4096 : 0);  // [c'][p]
        for (int tj = 0; tj < 4; tj++) {
            const int o = ob + tj * 16 + l16;
            const float bias = Bv[o];
            for (int ti = 0; ti < 4; ti++) {
                const int nl = ti * 16 + quad * 4;
                bf16 pv[4];
                for (int r = 0; r < 4; r++)
                    pv[r] = __float2bfloat16(acc[ti][tj][r] + bias);
                *(uint2*)&D2[o * 4096 + n0 + nl] = *(const uint2*)pv;
            }
        }
    }
}

// ---------------------------------------------------------------------------
// Kernel 2 (v2): S^T tiles: A=Kt (p rows), B=Q (q rows), K=256.
// global_load_lds staging (4 x 16B/thread/step), double-buffered LDS with
// counted s_waitcnt vmcnt(4), XOR swizzle (pre-swizzled global source +
// swizzled ds_read — measured 0 bank conflicts with this pattern in R3).
// D row = p_local -> pack 4 consecutive p as one uint2 store (4x fewer
// stores). Lsum: reduce over quads via shfl_xor(16,32); lanes<16 write
// Lpart[b][q][strip] (strip = 64-wide p range). No max-subtraction
// (|S|<=~10; clamp 80 inert).
// ---------------------------------------------------------------------------
__global__ __launch_bounds__(256, 4) void attn_s_kernel(
    const bf16* __restrict__ Qw, const bf16* __restrict__ Ktw,
    bf16* __restrict__ Pt, float* __restrict__ Lpart)
{
    // per buffer: Kt-tile 128x32 @ 0 (8KB), Q-tile 128x32 @ 4096 (8KB)
    __shared__ __align__(16) bf16 smem[2][8192];              // 32 KB

    const int b  = blockIdx.z;
    const int q0 = blockIdx.y * 128;
    const int p0 = blockIdx.x * 128;
    const bf16* Aq = Qw  + b * (4096 * 256);
    const bf16* Ak = Ktw + b * (4096 * 256);

    const int tid = threadIdx.x;
    const int wv = tid >> 6, lane = tid & 63, l16 = lane & 15, quad = lane >> 4;
    const int wr = wv >> 1, wc = wv & 1;                      // wr: p-half, wc: q-half

    // swizzled fragment-read offsets (bf16 units), constant over ks
    int aoff[4], boff[4];
    for (int t = 0; t < 4; t++) {
        const int rowa = wr * 64 + t * 16 + l16;              // p row
        aoff[t] = rowa * 32 + (quad ^ ((rowa >> 1) & 3)) * 8;
        const int rowb = wc * 64 + t * 16 + l16;              // q row
        boff[t] = rowb * 32 + (quad ^ ((rowb >> 1) & 3)) * 8;
    }

    // staging: 512 16B-slots per tile; thread t covers slots t and t+256
    const int arow0 = tid >> 2;                               // rows 0..63
    const int kswz = ((tid & 3) ^ ((arow0 >> 1) & 3)) * 8;    // same for row+64
    const bf16* Ag0 = Ak + (p0 + arow0) * 256 + kswz;
    const bf16* Ag1 = Ak + (p0 + 64 + arow0) * 256 + kswz;
    const bf16* Bg0 = Aq + (q0 + arow0) * 256 + kswz;
    const bf16* Bg1 = Aq + (q0 + 64 + arow0) * 256 + kswz;

    f32x4 acc[4][4] = {};

#define SSTAGE(buf, ks)                                                 \
    do {                                                                \
        const int _k = (ks) * 32;                                       \
        bf16* _s = &smem[(buf)][0];                                     \
        gld_lds16(Ag0 + _k, _s + tid * 8);                              \
        gld_lds16(Ag1 + _k, _s + 2048 + tid * 8);                       \
        gld_lds16(Bg0 + _k, _s + 4096 + tid * 8);                       \
        gld_lds16(Bg1 + _k, _s + 6144 + tid * 8);                       \
    } while (0)

    SSTAGE(0, 0);
    int cur = 0;
    for (int ks = 0; ks < 8; ks++) {
        if (ks + 1 < 8) {
            SSTAGE(cur ^ 1, ks + 1);
            asm volatile("s_waitcnt vmcnt(4)" ::: "memory");  // cur's 4 landed
        } else {
            asm volatile("s_waitcnt vmcnt(0)" ::: "memory");
        }
        __builtin_amdgcn_s_barrier();                         // all waves' cur landed
        __builtin_amdgcn_sched_barrier(0);

        const bf16* As_ = &smem[cur][0];
        const bf16* Bs_ = &smem[cur][4096];
        bf16x8 af[4], bfr[4];
        for (int t = 0; t < 4; t++) af[t]  = *(const bf16x8*)&As_[aoff[t]];
        for (int t = 0; t < 4; t++) bfr[t] = *(const bf16x8*)&Bs_[boff[t]];
        __builtin_amdgcn_s_setprio(1);
        for (int ti = 0; ti < 4; ti++)
            for (int tj = 0; tj < 4; tj++)
                acc[ti][tj] = __builtin_amdgcn_mfma_f32_16x16x32_bf16(af[ti], bfr[tj], acc[ti][tj], 0, 0, 0);
        __builtin_amdgcn_s_setprio(0);

        asm volatile("s_waitcnt lgkmcnt(0)" ::: "memory");    // LDS reads retired
        __builtin_amdgcn_s_barrier();                         // safe to overwrite cur
        cur ^= 1;
    }
#undef SSTAGE

    // Epilogue: exp, packed 8B stores (4 consecutive p per lane), L-partials.
    bf16* Pdst = Pt + (size_t)b * 4096 * 4096;
    const int strip = blockIdx.x * 2 + wr;                    // p strip of 64
    for (int tj = 0; tj < 4; tj++) {
        const int q = q0 + wc * 64 + tj * 16 + l16;           // D col = q
        float partial = 0.0f;
        for (int ti = 0; ti < 4; ti++) {
            const int p = p0 + wr * 64 + ti * 16 + quad * 4;  // D row = p
            bf16 pv[4];
            for (int r = 0; r < 4; r++) {
                const float e = __expf(fminf(acc[ti][tj][r], 80.0f));
                partial += e;
                pv[r] = __float2bfloat16(e);
            }
            *(uint2*)&Pdst[(size_t)q * 4096 + p] = *(const uint2*)pv;
        }
        // sum over the 4 quads (p sub-chunks) -> full 64-wide strip sum
        partial += __shfl_xor(partial, 16);
        partial += __shfl_xor(partial, 32);
        if (lane < 16)
            Lpart[(size_t)(b * 4096 + q) * 64 + strip] = partial;
    }
}

// ---------------------------------------------------------------------------
// Kernel 2b: Linv[b][q] = 1 / sum_strip Lpart  (8192 rows)
// ---------------------------------------------------------------------------
__global__ __launch_bounds__(256) void lred_kernel(
    const float* __restrict__ Lpart, float* __restrict__ Linv)
{
    const int row = blockIdx.x * 256 + threadIdx.x;           // [0, 8192)
    const float4* lp = (const float4*)&Lpart[(size_t)row * 64];
    float s = 0.0f;
    for (int i = 0; i < 16; i++) {
        const float4 v = lp[i];
        s += v.x + v.y + v.z + v.w;
    }
    Linv[row] = 1.0f / fmaxf(s, 1e-30f);
}

// ---------------------------------------------------------------------------
// Kernel 3: O = Vall.Pt^T (NT, K=4096) * Linv[q]. Tile 128c x 64q.
// v3 (reverted from v4 atomics): 512 thr = 2 K-split groups x 4 waves,
// double-buffered LDS + counted s_waitcnt vmcnt(3) + raw s_barrier.
// XOR swizzle (pre-swizzled global source + swizzled ds_read).
// Deterministic 2-group LDS combine, no atomics.
// ---------------------------------------------------------------------------
__global__ __launch_bounds__(512, 4) void attn_o_kernel(
    const bf16* __restrict__ Vall, const bf16* __restrict__ Pt,
    const float* __restrict__ Linv, float* __restrict__ out)
{
    // per group, per buffer: As[128][32] @ 0, Bs[64][32] @ 4096 (bf16 units)
    __shared__ __align__(16) bf16 smem[2][2][6144];           // 48 KB

    const int b  = blockIdx.z;
    const int c0 = blockIdx.y * 128;
    const int q0 = blockIdx.x * 64;
    const bf16* A = Vall + (size_t)b * 512 * 4096;
    const bf16* B = Pt   + (size_t)b * 4096 * 4096;

    const int tid = threadIdx.x;
    const int grp = tid >> 8;                                 // K-split group (2)
    const int t8  = tid & 255;
    const int wv = t8 >> 6, lane = t8 & 63, l16 = lane & 15, quad = lane >> 4;
    const int wr = wv >> 1, wc = wv & 1;                      // 64c x 32q quadrant

    // swizzled fragment-read offsets (bf16 units), constant over ks
    int aoff[4], boff[2];
    for (int t = 0; t < 4; t++) {
        const int row = wr * 64 + t * 16 + l16;
        aoff[t] = row * 32 + (quad ^ ((row >> 1) & 3)) * 8;
    }
    for (int t = 0; t < 2; t++) {
        const int row = wc * 32 + t * 16 + l16;
        boff[t] = row * 32 + (quad ^ ((row >> 1) & 3)) * 8;
    }

    const int arow = t8 >> 2;                                 // staged row (local)
    const int kswz = ((t8 & 3) ^ ((arow >> 1) & 3)) * 8;      // pre-swizzled k chunk
    const bf16* Ag0 = A + (c0 + arow) * 4096 + grp * 2048 + kswz;
    const bf16* Ag1 = A + (c0 + 64 + arow) * 4096 + grp * 2048 + kswz;
    const bf16* Bg  = B + (q0 + arow) * 4096 + grp * 2048 + kswz;

    f32x4 acc[4][2] = {};

#define STAGE(buf, ks)                                                  \
    do {                                                                \
        const int _k = (ks) * 32;                                       \
        bf16* _s = &smem[grp][(buf)][0];                                \
        gld_lds16(Ag0 + _k, _s + t8 * 8);                               \
        gld_lds16(Ag1 + _k, _s + 2048 + t8 * 8);                        \
        gld_lds16(Bg  + _k, _s + 4096 + t8 * 8);                        \
    } while (0)

    STAGE(0, 0);
    int cur = 0;
    for (int ks = 0; ks < 64; ks++) {
        if (ks + 1 < 64) {
            STAGE(cur ^ 1, ks + 1);
            asm volatile("s_waitcnt vmcnt(3)" ::: "memory");  // cur's 3 landed
        } else {
            asm volatile("s_waitcnt vmcnt(0)" ::: "memory");
        }
        __builtin_amdgcn_s_barrier();                         // all waves' cur landed
        __builtin_amdgcn_sched_barrier(0);

        const bf16* As_ = &smem[grp][cur][0];
        const bf16* Bs_ = &smem[grp][cur][4096];
        bf16x8 af[4], bfr[2];
        for (int t = 0; t < 4; t++) af[t]  = *(const bf16x8*)&As_[aoff[t]];
        for (int t = 0; t < 2; t++) bfr[t] = *(const bf16x8*)&Bs_[boff[t]];
        __builtin_amdgcn_s_setprio(1);
        for (int ti = 0; ti < 4; ti++)
            for (int tj = 0; tj < 2; tj++)
                acc[ti][tj] = __builtin_amdgcn_mfma_f32_16x16x32_bf16(af[ti], bfr[tj], acc[ti][tj], 0, 0, 0);
        __builtin_amdgcn_s_setprio(0);

        asm volatile("s_waitcnt lgkmcnt(0)" ::: "memory");    // LDS reads retired
        __builtin_amdgcn_s_barrier();                         // safe to overwrite cur
        cur ^= 1;
    }
#undef STAGE

    __syncthreads();                                          // full fence before LDS reuse

    // Deterministic cross-group combine in LDS (reuses staging space).
    float* comb = (float*)&smem[0][0];                        // [128 c][64 q] fp32 = 32 KB
    const int sl0 = (wr * 64 + quad * 4) * 64 + wc * 32 + l16;
    if (grp == 0) {
        for (int ti = 0; ti < 4; ti++)
            for (int tj = 0; tj < 2; tj++)
                for (int r = 0; r < 4; r++)
                    comb[sl0 + (ti * 16 + r) * 64 + tj * 16] = acc[ti][tj][r];
    }
    __syncthreads();
    if (grp == 1) {
        for (int ti = 0; ti < 4; ti++)
            for (int tj = 0; tj < 2; tj++)
                for (int r = 0; r < 4; r++)
                    comb[sl0 + (ti * 16 + r) * 64 + tj * 16] += acc[ti][tj][r];
    }
    __syncthreads();

    // All 512 threads: scale by Linv[q], store 16 consecutive q.
    const int f0 = tid * 16;
    const int cl = f0 >> 6, ql = f0 & 63;
    const int c_ = c0 + cl;
    const size_t base = (c_ < 256)
        ? ((size_t)b * 1048576 + (size_t)c_ * 4096)
        : (2097152u + (size_t)b * 1048576 + (size_t)(c_ - 256) * 4096);
    for (int j = 0; j < 4; j++) {
        const float4 v = *(const float4*)&comb[f0 + j * 4];
        const float4 l = *(const float4*)&Linv[b * 4096 + q0 + ql + j * 4];
        float4 o;
        o.x = v.x * l.x; o.y = v.y * l.y; o.z = v.z * l.z; o.w = v.w * l.w;
        *(float4*)&out[base + q0 + ql + j * 4] = o;
    }
}

// ---------------------------------------------------------------------------
// ws: [0,4)MB Q | [4,8)MB Kt | [8,16)MB Vall | [16,80)MB Pt |
//     [80,82)MB Lpart fp32 [2][4096][64] | [82MB,+32KB) Linv fp32 [2][4096]
// ---------------------------------------------------------------------------
extern "C" void kernel_launch(void* const* d_in, const int* in_sizes, int n_in,
                              void* d_out, int out_size, void* d_ws, size_t ws_size,
                              hipStream_t stream)
{
    const float* img = (const float*)d_in[0];
    const float* pc  = (const float*)d_in[1];
    const float* Wq  = (const float*)d_in[2];
    const float* bq  = (const float*)d_in[3];
    const float* Wk  = (const float*)d_in[4];
    const float* bk  = (const float*)d_in[5];
    const float* Wvi = (const float*)d_in[6];
    const float* bvi = (const float*)d_in[7];
    const float* Wvp = (const float*)d_in[8];
    const float* bvp = (const float*)d_in[9];

    char* ws = (char*)d_ws;
    bf16*  Qw    = (bf16*)(ws);
    bf16*  Ktw   = (bf16*)(ws + (4ull  << 20));
    bf16*  Vall  = (bf16*)(ws + (8ull  << 20));
    bf16*  Pt    = (bf16*)(ws + (16ull << 20));
    float* Lpart = (float*)(ws + (80ull << 20));
    float* Linv  = (float*)(ws + (82ull << 20));

    proj_kernel<<<512, 256, 0, stream>>>(img, pc, Wq, bq, Wk, bk,
                                         Wvi, bvi, Wvp, bvp, Qw, Ktw, Vall);
    attn_s_kernel<<<dim3(32, 32, 2), 256, 0, stream>>>(Qw, Ktw, Pt, Lpart);
    lred_kernel<<<32, 256, 0, stream>>>(Lpart, Linv);
    attn_o_kernel<<<dim3(64, 4, 2), 512, 0, stream>>>(Vall, Pt, Linv, (float*)d_out);
}

// Round 5
// 192.636 us; speedup vs baseline: 1.2765x; 1.0352x over previous
//
#include <hip/hip_runtime.h>
#include <hip/hip_bf16.h>

// B=2, IMG_DIM=VOXEL_DIM=QK_DIM=256, H=W=64, N=4096.
// Inputs/outputs FP32; internal GEMMs bf16 MFMA (16x16x32).

typedef __hip_bfloat16 bf16;
typedef __attribute__((ext_vector_type(8))) short bf16x8;   // 8 bf16 = 4 VGPRs
typedef __attribute__((ext_vector_type(4))) float f32x4;

#define AS1 __attribute__((address_space(1)))
#define AS3 __attribute__((address_space(3)))

__device__ __forceinline__ void gld_lds16(const bf16* g, bf16* s) {
    // async global->LDS, 16B/lane; LDS dst = wave-uniform base + lane*16
    __builtin_amdgcn_global_load_lds((const AS1 void*)g, (AS3 void*)s, 16, 0, 0);
}

__device__ __forceinline__ bf16x8 cvt8(const float* __restrict__ p) {
    const float4 a = *(const float4*)p;
    const float4 b = *(const float4*)(p + 4);
    bf16 t[8];
    t[0] = __float2bfloat16(a.x); t[1] = __float2bfloat16(a.y);
    t[2] = __float2bfloat16(a.z); t[3] = __float2bfloat16(a.w);
    t[4] = __float2bfloat16(b.x); t[5] = __float2bfloat16(b.y);
    t[6] = __float2bfloat16(b.z); t[7] = __float2bfloat16(b.w);
    return *(const bf16x8*)t;
}

// ---------------------------------------------------------------------------
// Kernel 1: projections. 512 blocks: blk = s*256 + b*128 + g*64 + ntile.
// Each block: one 64-position x 256-outch GEMM (g=0: Q/Kt; g=1: V).
// XT staged with coalesced float4 gathers (both layouts).
// ---------------------------------------------------------------------------
__global__ __launch_bounds__(256) void proj_kernel(
    const float* __restrict__ img, const float* __restrict__ pc,
    const float* __restrict__ Wq,  const float* __restrict__ bq,
    const float* __restrict__ Wk,  const float* __restrict__ bk,
    const float* __restrict__ Wvi, const float* __restrict__ bvi,
    const float* __restrict__ Wvp, const float* __restrict__ bvp,
    bf16* __restrict__ Qw, bf16* __restrict__ Ktw, bf16* __restrict__ Vall)
{
    __shared__ __align__(16) bf16 XT[64][264];   // [pos][cin], +8 pad

    const int blk = blockIdx.x;
    const int s   = blk >> 8;
    const int b   = (blk >> 7) & 1;
    const int g   = (blk >> 6) & 1;
    const int n0  = (blk & 63) * 64;
    const int tid = threadIdx.x;

    if (s == 0) {
        const float* src = img + b * 1048576;                 // [256][4096]
        for (int k = 0; k < 16; k++) {
            const int i = tid + k * 256;
            const int cin = i >> 4, nl4 = (i & 15) * 4;
            const float4 v = *(const float4*)&src[cin * 4096 + n0 + nl4];
            XT[nl4 + 0][cin] = __float2bfloat16(v.x);
            XT[nl4 + 1][cin] = __float2bfloat16(v.y);
            XT[nl4 + 2][cin] = __float2bfloat16(v.z);
            XT[nl4 + 3][cin] = __float2bfloat16(v.w);
        }
    } else {
        // pc[b][d][h][w][c]: ch = c*16+d, flat = d*65536 + n*16 + c
        const float* src = pc + b * 1048576;
        for (int k = 0; k < 16; k++) {
            const int d = k, u = tid;
            const int nl = u >> 2, c4 = (u & 3) * 4;
            const float4 v = *(const float4*)&src[d * 65536 + (n0 + nl) * 16 + c4];
            XT[nl][(c4 + 0) * 16 + d] = __float2bfloat16(v.x);
            XT[nl][(c4 + 1) * 16 + d] = __float2bfloat16(v.y);
            XT[nl][(c4 + 2) * 16 + d] = __float2bfloat16(v.z);
            XT[nl][(c4 + 3) * 16 + d] = __float2bfloat16(v.w);
        }
    }
    __syncthreads();

    const float* W = s ? (g ? Wvp : Wk) : (g ? Wvi : Wq);
    const float* Bv = s ? (g ? bvp : bk) : (g ? bvi : bq);

    const int wv = tid >> 6, lane = tid & 63, l16 = lane & 15, quad = lane >> 4;
    const int ob = wv * 64;

    f32x4 acc[4][4] = {};

    for (int ks = 0; ks < 8; ks++) {
        const int k0 = ks * 32;
        bf16x8 af[4], wf[4];
        for (int ti = 0; ti < 4; ti++)
            af[ti] = *(const bf16x8*)&XT[ti * 16 + l16][k0 + quad * 8];
        for (int tj = 0; tj < 4; tj++)
            wf[tj] = cvt8(&W[(ob + tj * 16 + l16) * 256 + k0 + quad * 8]);
        for (int ti = 0; ti < 4; ti++)
            for (int tj = 0; tj < 4; tj++)
                acc[ti][tj] = __builtin_amdgcn_mfma_f32_16x16x32_bf16(af[ti], wf[tj], acc[ti][tj], 0, 0, 0);
    }

    if (g == 0) {
        bf16* D1 = (s ? Ktw : Qw) + b * (4096 * 256);          // [n][o]
        for (int tj = 0; tj < 4; tj++) {
            const int o = ob + tj * 16 + l16;
            const float bias = Bv[o];
            for (int ti = 0; ti < 4; ti++) {
                const int nl = ti * 16 + quad * 4;             // D row = quad*4+r
                for (int r = 0; r < 4; r++)
                    D1[(n0 + nl + r) * 256 + o] = __float2bfloat16(acc[ti][tj][r] + bias);
            }
        }
    } else {
        bf16* D2 = Vall + b * (512 * 4096) + (s ? 256 * 4096 : 0);  // [c'][p]
        for (int tj = 0; tj < 4; tj++) {
            const int o = ob + tj * 16 + l16;
            const float bias = Bv[o];
            for (int ti = 0; ti < 4; ti++) {
                const int nl = ti * 16 + quad * 4;
                bf16 pv[4];
                for (int r = 0; r < 4; r++)
                    pv[r] = __float2bfloat16(acc[ti][tj][r] + bias);
                *(uint2*)&D2[o * 4096 + n0 + nl] = *(const uint2*)pv;
            }
        }
    }
}

// ---------------------------------------------------------------------------
// Kernel 2 (v2): S^T tiles: A=Kt (p rows), B=Q (q rows), K=256.
// global_load_lds staging, double-buffered, counted vmcnt(4), XOR swizzle.
// ---------------------------------------------------------------------------
__global__ __launch_bounds__(256, 4) void attn_s_kernel(
    const bf16* __restrict__ Qw, const bf16* __restrict__ Ktw,
    bf16* __restrict__ Pt, float* __restrict__ Lpart)
{
    // per buffer: Kt-tile 128x32 @ 0 (8KB), Q-tile 128x32 @ 4096 (8KB)
    __shared__ __align__(16) bf16 smem[2][8192];              // 32 KB

    const int b  = blockIdx.z;
    const int q0 = blockIdx.y * 128;
    const int p0 = blockIdx.x * 128;
    const bf16* Aq = Qw  + b * (4096 * 256);
    const bf16* Ak = Ktw + b * (4096 * 256);

    const int tid = threadIdx.x;
    const int wv = tid >> 6, lane = tid & 63, l16 = lane & 15, quad = lane >> 4;
    const int wr = wv >> 1, wc = wv & 1;                      // wr: p-half, wc: q-half

    // swizzled fragment-read offsets (bf16 units), constant over ks
    int aoff[4], boff[4];
    for (int t = 0; t < 4; t++) {
        const int rowa = wr * 64 + t * 16 + l16;              // p row
        aoff[t] = rowa * 32 + (quad ^ ((rowa >> 1) & 3)) * 8;
        const int rowb = wc * 64 + t * 16 + l16;              // q row
        boff[t] = rowb * 32 + (quad ^ ((rowb >> 1) & 3)) * 8;
    }

    // staging: 512 16B-slots per tile; thread t covers slots t and t+256
    const int arow0 = tid >> 2;                               // rows 0..63
    const int kswz = ((tid & 3) ^ ((arow0 >> 1) & 3)) * 8;    // same for row+64
    const bf16* Ag0 = Ak + (p0 + arow0) * 256 + kswz;
    const bf16* Ag1 = Ak + (p0 + 64 + arow0) * 256 + kswz;
    const bf16* Bg0 = Aq + (q0 + arow0) * 256 + kswz;
    const bf16* Bg1 = Aq + (q0 + 64 + arow0) * 256 + kswz;

    f32x4 acc[4][4] = {};

#define SSTAGE(buf, ks)                                                 \
    do {                                                                \
        const int _k = (ks) * 32;                                       \
        bf16* _s = &smem[(buf)][0];                                     \
        gld_lds16(Ag0 + _k, _s + tid * 8);                              \
        gld_lds16(Ag1 + _k, _s + 2048 + tid * 8);                       \
        gld_lds16(Bg0 + _k, _s + 4096 + tid * 8);                       \
        gld_lds16(Bg1 + _k, _s + 6144 + tid * 8);                       \
    } while (0)

    SSTAGE(0, 0);
    int cur = 0;
    for (int ks = 0; ks < 8; ks++) {
        if (ks + 1 < 8) {
            SSTAGE(cur ^ 1, ks + 1);
            asm volatile("s_waitcnt vmcnt(4)" ::: "memory");  // cur's 4 landed
        } else {
            asm volatile("s_waitcnt vmcnt(0)" ::: "memory");
        }
        __builtin_amdgcn_s_barrier();                         // all waves' cur landed
        __builtin_amdgcn_sched_barrier(0);

        const bf16* As_ = &smem[cur][0];
        const bf16* Bs_ = &smem[cur][4096];
        bf16x8 af[4], bfr[4];
        for (int t = 0; t < 4; t++) af[t]  = *(const bf16x8*)&As_[aoff[t]];
        for (int t = 0; t < 4; t++) bfr[t] = *(const bf16x8*)&Bs_[boff[t]];
        __builtin_amdgcn_s_setprio(1);
        for (int ti = 0; ti < 4; ti++)
            for (int tj = 0; tj < 4; tj++)
                acc[ti][tj] = __builtin_amdgcn_mfma_f32_16x16x32_bf16(af[ti], bfr[tj], acc[ti][tj], 0, 0, 0);
        __builtin_amdgcn_s_setprio(0);

        asm volatile("s_waitcnt lgkmcnt(0)" ::: "memory");    // LDS reads retired
        __builtin_amdgcn_s_barrier();                         // safe to overwrite cur
        cur ^= 1;
    }
#undef SSTAGE

    // Epilogue: exp, packed 8B stores (4 consecutive p per lane), L-partials.
    bf16* Pdst = Pt + (size_t)b * 4096 * 4096;
    const int strip = blockIdx.x * 2 + wr;                    // p strip of 64
    for (int tj = 0; tj < 4; tj++) {
        const int q = q0 + wc * 64 + tj * 16 + l16;           // D col = q
        float partial = 0.0f;
        for (int ti = 0; ti < 4; ti++) {
            const int p = p0 + wr * 64 + ti * 16 + quad * 4;  // D row = p
            bf16 pv[4];
            for (int r = 0; r < 4; r++) {
                const float e = __expf(fminf(acc[ti][tj][r], 80.0f));
                partial += e;
                pv[r] = __float2bfloat16(e);
            }
            *(uint2*)&Pdst[(size_t)q * 4096 + p] = *(const uint2*)pv;
        }
        // sum over the 4 quads (p sub-chunks) -> full 64-wide strip sum
        partial += __shfl_xor(partial, 16);
        partial += __shfl_xor(partial, 32);
        if (lane < 16)
            Lpart[(size_t)(b * 4096 + q) * 64 + strip] = partial;
    }
}

// ---------------------------------------------------------------------------
// Kernel 2b: Linv[b][q] = 1 / sum_strip Lpart  (8192 rows)
// ---------------------------------------------------------------------------
__global__ __launch_bounds__(256) void lred_kernel(
    const float* __restrict__ Lpart, float* __restrict__ Linv)
{
    const int row = blockIdx.x * 256 + threadIdx.x;           // [0, 8192)
    const float4* lp = (const float4*)&Lpart[(size_t)row * 64];
    float s = 0.0f;
    for (int i = 0; i < 16; i++) {
        const float4 v = lp[i];
        s += v.x + v.y + v.z + v.w;
    }
    Linv[row] = 1.0f / fmaxf(s, 1e-30f);
}

// ---------------------------------------------------------------------------
// Kernel 3: O = Vall.Pt^T (NT, K=4096) * Linv[q].
// v5: tile 128c x 128q (square -> staged bytes 768->512 MB, the R2-measured
// staging-rate ceiling is the binding constraint), 256 blocks (1/CU) x 512
// thr = 2 K-split groups x 4 waves (2x2 of 64x64 wave tiles; 8 ds_read_b128
// per 16 MFMA = 1.5x better LDS-read/FLOP than v3). Proven v3 pipeline:
// per-grp dbuf + counted vmcnt(4) + raw barriers + XOR swizzle. XCD chunk
// swizzle (256=8x32, bijective): the 4 c-tiles of one q-tile are consecutive
// in an XCD chunk -> Pt's 4x re-read served by that XCD's L2 (R3-verified
// locality mechanism). Deterministic 2-group LDS combine (comb = 64KB =
// exactly the staging LDS), no atomics.
// ---------------------------------------------------------------------------
__global__ __launch_bounds__(512, 2) void attn_o_kernel(
    const bf16* __restrict__ Vall, const bf16* __restrict__ Pt,
    const float* __restrict__ Linv, float* __restrict__ out)
{
    // [grp][buf]: As 128x32 @ 0 (4096 elems), Bs 128x32 @ 4096
    __shared__ __align__(16) bf16 smem[2][2][8192];           // 64 KB

    const int orig = blockIdx.x;
    const int L = (orig & 7) * 32 + (orig >> 3);              // XCD chunk swizzle
    const int b   = L >> 7;
    const int rem = L & 127;
    const int c0  = (rem & 3) * 128;
    const int q0  = (rem >> 2) * 128;

    const bf16* A = Vall + (size_t)b * 512 * 4096;
    const bf16* B = Pt   + (size_t)b * 4096 * 4096;

    const int tid = threadIdx.x;
    const int grp = tid >> 8;                                 // K-split group (2)
    const int t8  = tid & 255;
    const int wv = t8 >> 6, lane = t8 & 63, l16 = lane & 15, quad = lane >> 4;
    const int wr = wv >> 1, wc = wv & 1;                      // 64c x 64q wave tile

    // swizzled fragment-read offsets (bf16 units), constant over ks
    int aoff[4], boff[4];
    for (int t = 0; t < 4; t++) {
        const int rowa = wr * 64 + t * 16 + l16;
        aoff[t] = rowa * 32 + (quad ^ ((rowa >> 1) & 3)) * 8;
        const int rowb = wc * 64 + t * 16 + l16;
        boff[t] = rowb * 32 + (quad ^ ((rowb >> 1) & 3)) * 8;
    }

    const int arow = t8 >> 2;                                 // staged row (local)
    const int kswz = ((t8 & 3) ^ ((arow >> 1) & 3)) * 8;      // pre-swizzled k chunk
    const int kb = grp * 2048 + kswz;
    const bf16* Ag0 = A + (c0 + arow) * 4096 + kb;
    const bf16* Ag1 = A + (c0 + 64 + arow) * 4096 + kb;
    const bf16* Bg0 = B + (size_t)(q0 + arow) * 4096 + kb;
    const bf16* Bg1 = B + (size_t)(q0 + 64 + arow) * 4096 + kb;

    f32x4 acc[4][4] = {};

#define STAGE(buf, ks)                                                  \
    do {                                                                \
        const int _k = (ks) * 32;                                       \
        bf16* _s = &smem[grp][(buf)][0];                                \
        gld_lds16(Ag0 + _k, _s + t8 * 8);                               \
        gld_lds16(Ag1 + _k, _s + 2048 + t8 * 8);                        \
        gld_lds16(Bg0 + _k, _s + 4096 + t8 * 8);                        \
        gld_lds16(Bg1 + _k, _s + 6144 + t8 * 8);                        \
    } while (0)

    STAGE(0, 0);
    int cur = 0;
    for (int ks = 0; ks < 64; ks++) {
        if (ks + 1 < 64) {
            STAGE(cur ^ 1, ks + 1);
            asm volatile("s_waitcnt vmcnt(4)" ::: "memory");  // cur's 4 landed
        } else {
            asm volatile("s_waitcnt vmcnt(0)" ::: "memory");
        }
        __builtin_amdgcn_s_barrier();                         // all waves' cur landed
        __builtin_amdgcn_sched_barrier(0);

        const bf16* As_ = &smem[grp][cur][0];
        const bf16* Bs_ = &smem[grp][cur][4096];
        bf16x8 af[4], bfr[4];
        for (int t = 0; t < 4; t++) af[t]  = *(const bf16x8*)&As_[aoff[t]];
        for (int t = 0; t < 4; t++) bfr[t] = *(const bf16x8*)&Bs_[boff[t]];
        __builtin_amdgcn_s_setprio(1);
        for (int ti = 0; ti < 4; ti++)
            for (int tj = 0; tj < 4; tj++)
                acc[ti][tj] = __builtin_amdgcn_mfma_f32_16x16x32_bf16(af[ti], bfr[tj], acc[ti][tj], 0, 0, 0);
        __builtin_amdgcn_s_setprio(0);

        asm volatile("s_waitcnt lgkmcnt(0)" ::: "memory");    // LDS reads retired
        __builtin_amdgcn_s_barrier();                         // safe to overwrite cur
        cur ^= 1;
    }
#undef STAGE

    __syncthreads();                                          // full fence before LDS reuse

    // Deterministic cross-group combine in LDS (reuses staging space).
    float* comb = (float*)&smem[0][0][0];                     // [128 c][128 q] fp32 = 64 KB
    if (grp == 0) {
        for (int ti = 0; ti < 4; ti++)
            for (int tj = 0; tj < 4; tj++)
                for (int r = 0; r < 4; r++)
                    comb[(wr * 64 + ti * 16 + quad * 4 + r) * 128 + wc * 64 + tj * 16 + l16]
                        = acc[ti][tj][r];
    }
    __syncthreads();
    if (grp == 1) {
        for (int ti = 0; ti < 4; ti++)
            for (int tj = 0; tj < 4; tj++)
                for (int r = 0; r < 4; r++)
                    comb[(wr * 64 + ti * 16 + quad * 4 + r) * 128 + wc * 64 + tj * 16 + l16]
                        += acc[ti][tj][r];
    }
    __syncthreads();

    // All 512 threads: scale by Linv[q], store one c-row x 32 q segment.
    const int cl = tid >> 2, qb = (tid & 3) * 32;
    const int c_ = c0 + cl;
    const size_t base = (c_ < 256)
        ? ((size_t)b * 1048576 + (size_t)c_ * 4096)
        : (2097152u + (size_t)b * 1048576 + (size_t)(c_ - 256) * 4096);
    for (int j = 0; j < 8; j++) {
        const float4 v = *(const float4*)&comb[cl * 128 + qb + j * 4];
        const float4 l = *(const float4*)&Linv[b * 4096 + q0 + qb + j * 4];
        float4 o;
        o.x = v.x * l.x; o.y = v.y * l.y; o.z = v.z * l.z; o.w = v.w * l.w;
        *(float4*)&out[base + q0 + qb + j * 4] = o;
    }
}

// ---------------------------------------------------------------------------
// ws: [0,4)MB Q | [4,8)MB Kt | [8,16)MB Vall | [16,80)MB Pt |
//     [80,82)MB Lpart fp32 [2][4096][64] | [82MB,+32KB) Linv fp32 [2][4096]
// ---------------------------------------------------------------------------
extern "C" void kernel_launch(void* const* d_in, const int* in_sizes, int n_in,
                              void* d_out, int out_size, void* d_ws, size_t ws_size,
                              hipStream_t stream)
{
    const float* img = (const float*)d_in[0];
    const float* pc  = (const float*)d_in[1];
    const float* Wq  = (const float*)d_in[2];
    const float* bq  = (const float*)d_in[3];
    const float* Wk  = (const float*)d_in[4];
    const float* bk  = (const float*)d_in[5];
    const float* Wvi = (const float*)d_in[6];
    const float* bvi = (const float*)d_in[7];
    const float* Wvp = (const float*)d_in[8];
    const float* bvp = (const float*)d_in[9];

    char* ws = (char*)d_ws;
    bf16*  Qw    = (bf16*)(ws);
    bf16*  Ktw   = (bf16*)(ws + (4ull  << 20));
    bf16*  Vall  = (bf16*)(ws + (8ull  << 20));
    bf16*  Pt    = (bf16*)(ws + (16ull << 20));
    float* Lpart = (float*)(ws + (80ull << 20));
    float* Linv  = (float*)(ws + (82ull << 20));

    proj_kernel<<<512, 256, 0, stream>>>(img, pc, Wq, bq, Wk, bk,
                                         Wvi, bvi, Wvp, bvp, Qw, Ktw, Vall);
    attn_s_kernel<<<dim3(32, 32, 2), 256, 0, stream>>>(Qw, Ktw, Pt, Lpart);
    lred_kernel<<<32, 256, 0, stream>>>(Lpart, Linv);
    attn_o_kernel<<<256, 512, 0, stream>>>(Vall, Pt, Linv, (float*)d_out);
}

// Round 6
// 189.822 us; speedup vs baseline: 1.2955x; 1.0148x over previous
//
#include <hip/hip_runtime.h>
#include <hip/hip_bf16.h>

// B=2, IMG_DIM=VOXEL_DIM=QK_DIM=256, H=W=64, N=4096.
// Inputs/outputs FP32; internal GEMMs bf16 MFMA (16x16x32).

typedef __hip_bfloat16 bf16;
typedef __attribute__((ext_vector_type(8))) short bf16x8;   // 8 bf16 = 4 VGPRs
typedef __attribute__((ext_vector_type(4))) float f32x4;

#define AS1 __attribute__((address_space(1)))
#define AS3 __attribute__((address_space(3)))

__device__ __forceinline__ void gld_lds16(const bf16* g, bf16* s) {
    // async global->LDS, 16B/lane; LDS dst = wave-uniform base + lane*16
    __builtin_amdgcn_global_load_lds((const AS1 void*)g, (AS3 void*)s, 16, 0, 0);
}

__device__ __forceinline__ bf16x8 cvt8(const float* __restrict__ p) {
    const float4 a = *(const float4*)p;
    const float4 b = *(const float4*)(p + 4);
    bf16 t[8];
    t[0] = __float2bfloat16(a.x); t[1] = __float2bfloat16(a.y);
    t[2] = __float2bfloat16(a.z); t[3] = __float2bfloat16(a.w);
    t[4] = __float2bfloat16(b.x); t[5] = __float2bfloat16(b.y);
    t[6] = __float2bfloat16(b.z); t[7] = __float2bfloat16(b.w);
    return *(const bf16x8*)t;
}

// ---------------------------------------------------------------------------
// Kernel 1: projections. 512 blocks: blk = s*256 + b*128 + g*64 + ntile.
// Each block: one 64-position x 256-outch GEMM (g=0: Q/Kt; g=1: V).
// XT staged with coalesced float4 gathers (both layouts).
// ---------------------------------------------------------------------------
__global__ __launch_bounds__(256) void proj_kernel(
    const float* __restrict__ img, const float* __restrict__ pc,
    const float* __restrict__ Wq,  const float* __restrict__ bq,
    const float* __restrict__ Wk,  const float* __restrict__ bk,
    const float* __restrict__ Wvi, const float* __restrict__ bvi,
    const float* __restrict__ Wvp, const float* __restrict__ bvp,
    bf16* __restrict__ Qw, bf16* __restrict__ Ktw, bf16* __restrict__ Vall)
{
    __shared__ __align__(16) bf16 XT[64][264];   // [pos][cin], +8 pad

    const int blk = blockIdx.x;
    const int s   = blk >> 8;
    const int b   = (blk >> 7) & 1;
    const int g   = (blk >> 6) & 1;
    const int n0  = (blk & 63) * 64;
    const int tid = threadIdx.x;

    if (s == 0) {
        const float* src = img + b * 1048576;                 // [256][4096]
        for (int k = 0; k < 16; k++) {
            const int i = tid + k * 256;
            const int cin = i >> 4, nl4 = (i & 15) * 4;
            const float4 v = *(const float4*)&src[cin * 4096 + n0 + nl4];
            XT[nl4 + 0][cin] = __float2bfloat16(v.x);
            XT[nl4 + 1][cin] = __float2bfloat16(v.y);
            XT[nl4 + 2][cin] = __float2bfloat16(v.z);
            XT[nl4 + 3][cin] = __float2bfloat16(v.w);
        }
    } else {
        // pc[b][d][h][w][c]: ch = c*16+d, flat = d*65536 + n*16 + c
        const float* src = pc + b * 1048576;
        for (int k = 0; k < 16; k++) {
            const int d = k, u = tid;
            const int nl = u >> 2, c4 = (u & 3) * 4;
            const float4 v = *(const float4*)&src[d * 65536 + (n0 + nl) * 16 + c4];
            XT[nl][(c4 + 0) * 16 + d] = __float2bfloat16(v.x);
            XT[nl][(c4 + 1) * 16 + d] = __float2bfloat16(v.y);
            XT[nl][(c4 + 2) * 16 + d] = __float2bfloat16(v.z);
            XT[nl][(c4 + 3) * 16 + d] = __float2bfloat16(v.w);
        }
    }
    __syncthreads();

    const float* W = s ? (g ? Wvp : Wk) : (g ? Wvi : Wq);
    const float* Bv = s ? (g ? bvp : bk) : (g ? bvi : bq);

    const int wv = tid >> 6, lane = tid & 63, l16 = lane & 15, quad = lane >> 4;
    const int ob = wv * 64;

    f32x4 acc[4][4] = {};

    for (int ks = 0; ks < 8; ks++) {
        const int k0 = ks * 32;
        bf16x8 af[4], wf[4];
        for (int ti = 0; ti < 4; ti++)
            af[ti] = *(const bf16x8*)&XT[ti * 16 + l16][k0 + quad * 8];
        for (int tj = 0; tj < 4; tj++)
            wf[tj] = cvt8(&W[(ob + tj * 16 + l16) * 256 + k0 + quad * 8]);
        for (int ti = 0; ti < 4; ti++)
            for (int tj = 0; tj < 4; tj++)
                acc[ti][tj] = __builtin_amdgcn_mfma_f32_16x16x32_bf16(af[ti], wf[tj], acc[ti][tj], 0, 0, 0);
    }

    if (g == 0) {
        bf16* D1 = (s ? Ktw : Qw) + b * (4096 * 256);          // [n][o]
        for (int tj = 0; tj < 4; tj++) {
            const int o = ob + tj * 16 + l16;
            const float bias = Bv[o];
            for (int ti = 0; ti < 4; ti++) {
                const int nl = ti * 16 + quad * 4;             // D row = quad*4+r
                for (int r = 0; r < 4; r++)
                    D1[(n0 + nl + r) * 256 + o] = __float2bfloat16(acc[ti][tj][r] + bias);
            }
        }
    } else {
        bf16* D2 = Vall + b * (512 * 4096) + (s ? 256 * 4096 : 0);  // [c'][p]
        for (int tj = 0; tj < 4; tj++) {
            const int o = ob + tj * 16 + l16;
            const float bias = Bv[o];
            for (int ti = 0; ti < 4; ti++) {
                const int nl = ti * 16 + quad * 4;
                bf16 pv[4];
                for (int r = 0; r < 4; r++)
                    pv[r] = __float2bfloat16(acc[ti][tj][r] + bias);
                *(uint2*)&D2[o * 4096 + n0 + nl] = *(const uint2*)pv;
            }
        }
    }
}

// ---------------------------------------------------------------------------
// Kernel 2 (v2): S^T tiles: A=Kt (p rows), B=Q (q rows), K=256.
// global_load_lds staging, double-buffered, counted vmcnt(4), XOR swizzle.
// ---------------------------------------------------------------------------
__global__ __launch_bounds__(256, 4) void attn_s_kernel(
    const bf16* __restrict__ Qw, const bf16* __restrict__ Ktw,
    bf16* __restrict__ Pt, float* __restrict__ Lpart)
{
    // per buffer: Kt-tile 128x32 @ 0 (8KB), Q-tile 128x32 @ 4096 (8KB)
    __shared__ __align__(16) bf16 smem[2][8192];              // 32 KB

    const int b  = blockIdx.z;
    const int q0 = blockIdx.y * 128;
    const int p0 = blockIdx.x * 128;
    const bf16* Aq = Qw  + b * (4096 * 256);
    const bf16* Ak = Ktw + b * (4096 * 256);

    const int tid = threadIdx.x;
    const int wv = tid >> 6, lane = tid & 63, l16 = lane & 15, quad = lane >> 4;
    const int wr = wv >> 1, wc = wv & 1;                      // wr: p-half, wc: q-half

    // swizzled fragment-read offsets (bf16 units), constant over ks
    int aoff[4], boff[4];
    for (int t = 0; t < 4; t++) {
        const int rowa = wr * 64 + t * 16 + l16;              // p row
        aoff[t] = rowa * 32 + (quad ^ ((rowa >> 1) & 3)) * 8;
        const int rowb = wc * 64 + t * 16 + l16;              // q row
        boff[t] = rowb * 32 + (quad ^ ((rowb >> 1) & 3)) * 8;
    }

    // staging: 512 16B-slots per tile; thread t covers slots t and t+256
    const int arow0 = tid >> 2;                               // rows 0..63
    const int kswz = ((tid & 3) ^ ((arow0 >> 1) & 3)) * 8;    // same for row+64
    const bf16* Ag0 = Ak + (p0 + arow0) * 256 + kswz;
    const bf16* Ag1 = Ak + (p0 + 64 + arow0) * 256 + kswz;
    const bf16* Bg0 = Aq + (q0 + arow0) * 256 + kswz;
    const bf16* Bg1 = Aq + (q0 + 64 + arow0) * 256 + kswz;

    f32x4 acc[4][4] = {};

#define SSTAGE(buf, ks)                                                 \
    do {                                                                \
        const int _k = (ks) * 32;                                       \
        bf16* _s = &smem[(buf)][0];                                     \
        gld_lds16(Ag0 + _k, _s + tid * 8);                              \
        gld_lds16(Ag1 + _k, _s + 2048 + tid * 8);                       \
        gld_lds16(Bg0 + _k, _s + 4096 + tid * 8);                       \
        gld_lds16(Bg1 + _k, _s + 6144 + tid * 8);                       \
    } while (0)

    SSTAGE(0, 0);
    int cur = 0;
    for (int ks = 0; ks < 8; ks++) {
        if (ks + 1 < 8) {
            SSTAGE(cur ^ 1, ks + 1);
            asm volatile("s_waitcnt vmcnt(4)" ::: "memory");  // cur's 4 landed
        } else {
            asm volatile("s_waitcnt vmcnt(0)" ::: "memory");
        }
        __builtin_amdgcn_s_barrier();                         // all waves' cur landed
        __builtin_amdgcn_sched_barrier(0);

        const bf16* As_ = &smem[cur][0];
        const bf16* Bs_ = &smem[cur][4096];
        bf16x8 af[4], bfr[4];
        for (int t = 0; t < 4; t++) af[t]  = *(const bf16x8*)&As_[aoff[t]];
        for (int t = 0; t < 4; t++) bfr[t] = *(const bf16x8*)&Bs_[boff[t]];
        __builtin_amdgcn_s_setprio(1);
        for (int ti = 0; ti < 4; ti++)
            for (int tj = 0; tj < 4; tj++)
                acc[ti][tj] = __builtin_amdgcn_mfma_f32_16x16x32_bf16(af[ti], bfr[tj], acc[ti][tj], 0, 0, 0);
        __builtin_amdgcn_s_setprio(0);

        asm volatile("s_waitcnt lgkmcnt(0)" ::: "memory");    // LDS reads retired
        __builtin_amdgcn_s_barrier();                         // safe to overwrite cur
        cur ^= 1;
    }
#undef SSTAGE

    // Epilogue: exp, packed 8B stores (4 consecutive p per lane), L-partials.
    bf16* Pdst = Pt + (size_t)b * 4096 * 4096;
    const int strip = blockIdx.x * 2 + wr;                    // p strip of 64
    for (int tj = 0; tj < 4; tj++) {
        const int q = q0 + wc * 64 + tj * 16 + l16;           // D col = q
        float partial = 0.0f;
        for (int ti = 0; ti < 4; ti++) {
            const int p = p0 + wr * 64 + ti * 16 + quad * 4;  // D row = p
            bf16 pv[4];
            for (int r = 0; r < 4; r++) {
                const float e = __expf(fminf(acc[ti][tj][r], 80.0f));
                partial += e;
                pv[r] = __float2bfloat16(e);
            }
            *(uint2*)&Pdst[(size_t)q * 4096 + p] = *(const uint2*)pv;
        }
        // sum over the 4 quads (p sub-chunks) -> full 64-wide strip sum
        partial += __shfl_xor(partial, 16);
        partial += __shfl_xor(partial, 32);
        if (lane < 16)
            Lpart[(size_t)(b * 4096 + q) * 64 + strip] = partial;
    }
}

// ---------------------------------------------------------------------------
// Kernel 2b: Linv[b][q] = 1 / sum_strip Lpart  (8192 rows)
// ---------------------------------------------------------------------------
__global__ __launch_bounds__(256) void lred_kernel(
    const float* __restrict__ Lpart, float* __restrict__ Linv)
{
    const int row = blockIdx.x * 256 + threadIdx.x;           // [0, 8192)
    const float4* lp = (const float4*)&Lpart[(size_t)row * 64];
    float s = 0.0f;
    for (int i = 0; i < 16; i++) {
        const float4 v = lp[i];
        s += v.x + v.y + v.z + v.w;
    }
    Linv[row] = 1.0f / fmaxf(s, 1e-30f);
}

// ---------------------------------------------------------------------------
// Kernel 3: O = Vall.Pt^T (NT, K=4096) * Linv[q].
// v6: v5 geometry (128c x 128q tile, 256 blocks, 512 thr = 2 K-split groups
// x 4 waves) with QUAD-buffered LDS (depth-4 prefetch). R5 showed iter time
// 2270cy vs ~500cy compute: with 2 buffers the consumed stage was issued
// only 1 iter earlier -> exposed LLC queueing latency. Depth 4: prologue
// stages 0-2; iter ks issues stage ks+3, waits vmcnt(12) (3 stages = 12
// load-instrs in flight; consumed stage had 3 iters to land). LDS = 2 grp x
// 4 buf x 16KB = 128KB (gfx950 LDS 160KB/CU; occupancy already 1 blk/CU).
// XOR swizzle + XCD chunk swizzle + deterministic 2-group combine as v5.
// ---------------------------------------------------------------------------
__global__ __launch_bounds__(512, 2) void attn_o_kernel(
    const bf16* __restrict__ Vall, const bf16* __restrict__ Pt,
    const float* __restrict__ Linv, float* __restrict__ out)
{
    // [grp][buf]: As 128x32 @ 0 (4096 elems), Bs 128x32 @ 4096
    __shared__ __align__(16) bf16 smem[2][4][8192];           // 128 KB

    const int orig = blockIdx.x;
    const int L = (orig & 7) * 32 + (orig >> 3);              // XCD chunk swizzle
    const int b   = L >> 7;
    const int rem = L & 127;
    const int c0  = (rem & 3) * 128;
    const int q0  = (rem >> 2) * 128;

    const bf16* A = Vall + (size_t)b * 512 * 4096;
    const bf16* B = Pt   + (size_t)b * 4096 * 4096;

    const int tid = threadIdx.x;
    const int grp = tid >> 8;                                 // K-split group (2)
    const int t8  = tid & 255;
    const int wv = t8 >> 6, lane = t8 & 63, l16 = lane & 15, quad = lane >> 4;
    const int wr = wv >> 1, wc = wv & 1;                      // 64c x 64q wave tile

    // swizzled fragment-read offsets (bf16 units), constant over ks
    int aoff[4], boff[4];
    for (int t = 0; t < 4; t++) {
        const int rowa = wr * 64 + t * 16 + l16;
        aoff[t] = rowa * 32 + (quad ^ ((rowa >> 1) & 3)) * 8;
        const int rowb = wc * 64 + t * 16 + l16;
        boff[t] = rowb * 32 + (quad ^ ((rowb >> 1) & 3)) * 8;
    }

    const int arow = t8 >> 2;                                 // staged row (local)
    const int kswz = ((t8 & 3) ^ ((arow >> 1) & 3)) * 8;      // pre-swizzled k chunk
    const int kb = grp * 2048 + kswz;
    const bf16* Ag0 = A + (c0 + arow) * 4096 + kb;
    const bf16* Ag1 = A + (c0 + 64 + arow) * 4096 + kb;
    const bf16* Bg0 = B + (size_t)(q0 + arow) * 4096 + kb;
    const bf16* Bg1 = B + (size_t)(q0 + 64 + arow) * 4096 + kb;

    f32x4 acc[4][4] = {};

#define STAGE(buf, ks)                                                  \
    do {                                                                \
        const int _k = (ks) * 32;                                       \
        bf16* _s = &smem[grp][(buf)][0];                                \
        gld_lds16(Ag0 + _k, _s + t8 * 8);                               \
        gld_lds16(Ag1 + _k, _s + 2048 + t8 * 8);                        \
        gld_lds16(Bg0 + _k, _s + 4096 + t8 * 8);                        \
        gld_lds16(Bg1 + _k, _s + 6144 + t8 * 8);                        \
    } while (0)

    STAGE(0, 0);
    STAGE(1, 1);
    STAGE(2, 2);
    for (int ks = 0; ks < 64; ks++) {
        // depth-4 counted prefetch: consumed stage ks was issued 3 iters ago
        if (ks + 3 < 64) {
            STAGE((ks + 3) & 3, ks + 3);
            asm volatile("s_waitcnt vmcnt(12)" ::: "memory"); // stage ks landed
        } else if (ks + 2 < 64) {
            asm volatile("s_waitcnt vmcnt(8)" ::: "memory");
        } else if (ks + 1 < 64) {
            asm volatile("s_waitcnt vmcnt(4)" ::: "memory");
        } else {
            asm volatile("s_waitcnt vmcnt(0)" ::: "memory");
        }
        __builtin_amdgcn_s_barrier();                         // all waves' stage ks landed
        __builtin_amdgcn_sched_barrier(0);

        const bf16* As_ = &smem[grp][ks & 3][0];
        const bf16* Bs_ = &smem[grp][ks & 3][4096];
        bf16x8 af[4], bfr[4];
        for (int t = 0; t < 4; t++) af[t]  = *(const bf16x8*)&As_[aoff[t]];
        for (int t = 0; t < 4; t++) bfr[t] = *(const bf16x8*)&Bs_[boff[t]];
        __builtin_amdgcn_s_setprio(1);
        for (int ti = 0; ti < 4; ti++)
            for (int tj = 0; tj < 4; tj++)
                acc[ti][tj] = __builtin_amdgcn_mfma_f32_16x16x32_bf16(af[ti], bfr[tj], acc[ti][tj], 0, 0, 0);
        __builtin_amdgcn_s_setprio(0);

        asm volatile("s_waitcnt lgkmcnt(0)" ::: "memory");    // LDS reads retired
        __builtin_amdgcn_s_barrier();                         // safe to overwrite buf (ks+4)&3 == this one
    }
#undef STAGE

    __syncthreads();                                          // full fence before LDS reuse

    // Deterministic cross-group combine in LDS (reuses staging space).
    float* comb = (float*)&smem[0][0][0];                     // [128 c][128 q] fp32 = 64 KB
    if (grp == 0) {
        for (int ti = 0; ti < 4; ti++)
            for (int tj = 0; tj < 4; tj++)
                for (int r = 0; r < 4; r++)
                    comb[(wr * 64 + ti * 16 + quad * 4 + r) * 128 + wc * 64 + tj * 16 + l16]
                        = acc[ti][tj][r];
    }
    __syncthreads();
    if (grp == 1) {
        for (int ti = 0; ti < 4; ti++)
            for (int tj = 0; tj < 4; tj++)
                for (int r = 0; r < 4; r++)
                    comb[(wr * 64 + ti * 16 + quad * 4 + r) * 128 + wc * 64 + tj * 16 + l16]
                        += acc[ti][tj][r];
    }
    __syncthreads();

    // All 512 threads: scale by Linv[q], store one c-row x 32 q segment.
    const int cl = tid >> 2, qb = (tid & 3) * 32;
    const int c_ = c0 + cl;
    const size_t base = (c_ < 256)
        ? ((size_t)b * 1048576 + (size_t)c_ * 4096)
        : (2097152u + (size_t)b * 1048576 + (size_t)(c_ - 256) * 4096);
    for (int j = 0; j < 8; j++) {
        const float4 v = *(const float4*)&comb[cl * 128 + qb + j * 4];
        const float4 l = *(const float4*)&Linv[b * 4096 + q0 + qb + j * 4];
        float4 o;
        o.x = v.x * l.x; o.y = v.y * l.y; o.z = v.z * l.z; o.w = v.w * l.w;
        *(float4*)&out[base + q0 + qb + j * 4] = o;
    }
}

// ---------------------------------------------------------------------------
// ws: [0,4)MB Q | [4,8)MB Kt | [8,16)MB Vall | [16,80)MB Pt |
//     [80,82)MB Lpart fp32 [2][4096][64] | [82MB,+32KB) Linv fp32 [2][4096]
// ---------------------------------------------------------------------------
extern "C" void kernel_launch(void* const* d_in, const int* in_sizes, int n_in,
                              void* d_out, int out_size, void* d_ws, size_t ws_size,
                              hipStream_t stream)
{
    const float* img = (const float*)d_in[0];
    const float* pc  = (const float*)d_in[1];
    const float* Wq  = (const float*)d_in[2];
    const float* bq  = (const float*)d_in[3];
    const float* Wk  = (const float*)d_in[4];
    const float* bk  = (const float*)d_in[5];
    const float* Wvi = (const float*)d_in[6];
    const float* bvi = (const float*)d_in[7];
    const float* Wvp = (const float*)d_in[8];
    const float* bvp = (const float*)d_in[9];

    char* ws = (char*)d_ws;
    bf16*  Qw    = (bf16*)(ws);
    bf16*  Ktw   = (bf16*)(ws + (4ull  << 20));
    bf16*  Vall  = (bf16*)(ws + (8ull  << 20));
    bf16*  Pt    = (bf16*)(ws + (16ull << 20));
    float* Lpart = (float*)(ws + (80ull << 20));
    float* Linv  = (float*)(ws + (82ull << 20));

    proj_kernel<<<512, 256, 0, stream>>>(img, pc, Wq, bq, Wk, bk,
                                         Wvi, bvi, Wvp, bvp, Qw, Ktw, Vall);
    attn_s_kernel<<<dim3(32, 32, 2), 256, 0, stream>>>(Qw, Ktw, Pt, Lpart);
    lred_kernel<<<32, 256, 0, stream>>>(Lpart, Linv);
    attn_o_kernel<<<256, 512, 0, stream>>>(Vall, Pt, Linv, (float*)d_out);
}